// Round 9
// baseline (180.596 us; speedup 1.0000x reference)
//
#include <hip/hip_runtime.h>
#include <hip/hip_bf16.h>

#define PAD_IDX 0
#define SEQ_L 64
#define ROWS_PER_BLOCK 64
#define THREADS 256
// per-row LDS stride in int4 units: 16 data + 1 pad (16B) to spread banks
#define ROW_STRIDE4 17

typedef int   v4i __attribute__((ext_vector_type(4)));
typedef uint  v2u __attribute__((ext_vector_type(2)));
typedef float v4f __attribute__((ext_vector_type(4)));

__device__ __forceinline__ float bf16_lo(unsigned int w) {
    return __uint_as_float(w << 16);
}
__device__ __forceinline__ float bf16_hi(unsigned int w) {
    return __uint_as_float(w & 0xffff0000u);
}

// ---- Pass 1: convert fp32 table -> packed bf16 table in workspace (L2-resident).
__global__ __launch_bounds__(256) void convert_bf16_kernel(
    const float* __restrict__ emb, ushort* __restrict__ tab, int n /* elements */)
{
    int i4 = (blockIdx.x * 256 + threadIdx.x) * 4;
    if (i4 + 3 < n) {
        float4 v = *reinterpret_cast<const float4*>(emb + i4);
        ushort4 o;
        o.x = __bfloat16_as_ushort(__float2bfloat16(v.x));
        o.y = __bfloat16_as_ushort(__float2bfloat16(v.y));
        o.z = __bfloat16_as_ushort(__float2bfloat16(v.z));
        o.w = __bfloat16_as_ushort(__float2bfloat16(v.w));
        *reinterpret_cast<ushort4*>(tab + i4) = o;
    } else if (i4 < n) {
        for (int k = i4; k < n; ++k)
            tab[k] = __bfloat16_as_ushort(__float2bfloat16(emb[k]));
    }
}

// ---- Pass 2: R7 structure; gathers are NON-TEMPORAL (no L1 allocation).
__global__ __launch_bounds__(THREADS, 6) void visit_encoder_bf16v6_kernel(
    const int* __restrict__ code_ids,
    const v2u* __restrict__ tab,     // bf16 table, row = 32B = 4 x v2u
    float* __restrict__ out,
    int B, int n_codes4)
{
    __shared__ v4i lcodes[ROWS_PER_BLOCK * ROW_STRIDE4];  // 17408 B

    const int t = threadIdx.x;
    const int block_row0 = blockIdx.x * ROWS_PER_BLOCK;

    // Stage 64 rows x 64 codes = 1024 int4; coalesced, regular (cached) loads.
    const v4i* src4 = reinterpret_cast<const v4i*>(code_ids);
    const int base4 = blockIdx.x * (ROWS_PER_BLOCK * SEQ_L / 4);
    #pragma unroll
    for (int k = 0; k < 4; ++k) {
        int j = t + THREADS * k;                 // 0..1023
        int gj = base4 + j;
        if (gj >= n_codes4) gj = n_codes4 - 1;   // tail clamp (ids stay valid)
        v4i v = src4[gj];
        lcodes[(j >> 4) * ROW_STRIDE4 + (j & 15)] = v;
    }
    __syncthreads();

    const int r  = t >> 2;     // 0..63 row within block
    const int d4 = t & 3;      // quarter-row: dims 4*d4 .. 4*d4+3
    const v2u* tbase = tab + d4;   // element index = code*4 + d4

    float acc[4] = {0.f, 0.f, 0.f, 0.f};
    int cnt = 0;

    // 5 batches of 12 codes (12 x 8B NT gathers in flight), then a tail of 4.
    #pragma unroll
    for (int b = 0; b < 5; ++b) {
        v4i c0 = lcodes[r * ROW_STRIDE4 + b * 3 + 0];
        v4i c1 = lcodes[r * ROW_STRIDE4 + b * 3 + 1];
        v4i c2 = lcodes[r * ROW_STRIDE4 + b * 3 + 2];
        int cc[12] = {c0.x, c0.y, c0.z, c0.w,
                      c1.x, c1.y, c1.z, c1.w,
                      c2.x, c2.y, c2.z, c2.w};
        v2u e[12];
        #pragma unroll
        for (int u = 0; u < 12; ++u) {
            e[u] = __builtin_nontemporal_load(tbase + (size_t)cc[u] * 4);
        }
        #pragma unroll
        for (int u = 0; u < 12; ++u) {
            float m = (cc[u] != PAD_IDX) ? 1.0f : 0.0f;
            acc[0] = fmaf(bf16_lo(e[u].x), m, acc[0]);
            acc[1] = fmaf(bf16_hi(e[u].x), m, acc[1]);
            acc[2] = fmaf(bf16_lo(e[u].y), m, acc[2]);
            acc[3] = fmaf(bf16_hi(e[u].y), m, acc[3]);
            cnt += (cc[u] != PAD_IDX);
        }
    }
    {   // tail: codes 60..63 (int4 index 15)
        v4i c0 = lcodes[r * ROW_STRIDE4 + 15];
        int cc[4] = {c0.x, c0.y, c0.z, c0.w};
        v2u e[4];
        #pragma unroll
        for (int u = 0; u < 4; ++u)
            e[u] = __builtin_nontemporal_load(tbase + (size_t)cc[u] * 4);
        #pragma unroll
        for (int u = 0; u < 4; ++u) {
            float m = (cc[u] != PAD_IDX) ? 1.0f : 0.0f;
            acc[0] = fmaf(bf16_lo(e[u].x), m, acc[0]);
            acc[1] = fmaf(bf16_hi(e[u].x), m, acc[1]);
            acc[2] = fmaf(bf16_lo(e[u].y), m, acc[2]);
            acc[3] = fmaf(bf16_hi(e[u].y), m, acc[3]);
            cnt += (cc[u] != PAD_IDX);
        }
    }

    const int row = block_row0 + r;
    if (row < B) {
        float inv = 1.0f / fmaxf((float)cnt, 1.0f);
        v4f o;
        o.x = acc[0]*inv; o.y = acc[1]*inv; o.z = acc[2]*inv; o.w = acc[3]*inv;
        v4f* op = reinterpret_cast<v4f*>(out) + (size_t)row * 4 + d4;
        __builtin_nontemporal_store(o, op);
    }
}

// ---- Fallback: direct fp32 gather (proven R2 kernel) if ws too small.
__global__ __launch_bounds__(256) void visit_encoder_f32_kernel(
    const int* __restrict__ code_ids,
    const float* __restrict__ emb,
    float* __restrict__ out,
    int B, int n_codes4)
{
    __shared__ int4 lcodes[64 * 17];
    const int t = threadIdx.x;
    const int block_row0 = blockIdx.x * 64;
    const int4* src4 = reinterpret_cast<const int4*>(code_ids);
    const int base4 = blockIdx.x * (64 * SEQ_L / 4);
    #pragma unroll
    for (int k = 0; k < 4; ++k) {
        int j = t + 256 * k;
        int gj = base4 + j;
        if (gj >= n_codes4) gj = n_codes4 - 1;
        lcodes[(j >> 4) * 17 + (j & 15)] = src4[gj];
    }
    __syncthreads();
    const int r  = t >> 2;
    const int d4 = t & 3;
    const float4* ebase = reinterpret_cast<const float4*>(emb) + d4;
    float4 acc = make_float4(0.f, 0.f, 0.f, 0.f);
    int cnt = 0;
    #pragma unroll
    for (int l4 = 0; l4 < 16; l4 += 2) {
        int4 ca = lcodes[r * 17 + l4];
        int4 cb = lcodes[r * 17 + l4 + 1];
        int csx[8] = {ca.x, ca.y, ca.z, ca.w, cb.x, cb.y, cb.z, cb.w};
        float4 e[8];
        #pragma unroll
        for (int u = 0; u < 8; ++u) e[u] = ebase[(size_t)csx[u] * 4];
        #pragma unroll
        for (int u = 0; u < 8; ++u) {
            float m = (csx[u] != PAD_IDX) ? 1.0f : 0.0f;
            acc.x = fmaf(e[u].x, m, acc.x);
            acc.y = fmaf(e[u].y, m, acc.y);
            acc.z = fmaf(e[u].z, m, acc.z);
            acc.w = fmaf(e[u].w, m, acc.w);
            cnt += (csx[u] != PAD_IDX);
        }
    }
    const int row = block_row0 + r;
    if (row < B) {
        float inv = 1.0f / fmaxf((float)cnt, 1.0f);
        float4 o;
        o.x = acc.x * inv; o.y = acc.y * inv; o.z = acc.z * inv; o.w = acc.w * inv;
        reinterpret_cast<float4*>(out)[(size_t)row * 4 + d4] = o;
    }
}

extern "C" void kernel_launch(void* const* d_in, const int* in_sizes, int n_in,
                              void* d_out, int out_size, void* d_ws, size_t ws_size,
                              hipStream_t stream) {
    const int*   code_ids = (const int*)d_in[0];
    const float* emb      = (const float*)d_in[1];
    float*       out      = (float*)d_out;

    const int total_codes = in_sizes[0];        // B * L
    const int B = total_codes / SEQ_L;
    const int n_codes4 = total_codes / 4;
    const int emb_elems = in_sizes[1];          // NUM_CODES * DIM

    const size_t tab_bytes = (size_t)emb_elems * sizeof(ushort);
    if (ws_size >= tab_bytes) {
        ushort* tab = (ushort*)d_ws;
        int n4 = (emb_elems + 3) / 4;
        convert_bf16_kernel<<<dim3((n4 + 255) / 256), dim3(256), 0, stream>>>(
            emb, tab, emb_elems);
        const int grid = (B + ROWS_PER_BLOCK - 1) / ROWS_PER_BLOCK;
        visit_encoder_bf16v6_kernel<<<dim3(grid), dim3(THREADS), 0, stream>>>(
            code_ids, (const v2u*)tab, out, B, n_codes4);
    } else {
        const int grid = (B + 63) / 64;
        visit_encoder_f32_kernel<<<dim3(grid), dim3(256), 0, stream>>>(
            code_ids, emb, out, B, n_codes4);
    }
}

// Round 12
// 67.761 us; speedup vs baseline: 2.6652x; 2.6652x over previous
//
#include <hip/hip_runtime.h>
#include <hip/hip_bf16.h>

#define PAD_IDX 0
#define SEQ_L 64
#define ROWS_PER_BLOCK 64
#define THREADS 256
// per-row LDS stride in int4 units: 16 data + 1 pad (16B) to spread banks
#define ROW_STRIDE4 17

typedef int   v4i __attribute__((ext_vector_type(4)));
typedef uint  v2u __attribute__((ext_vector_type(2)));
typedef float v4f __attribute__((ext_vector_type(4)));

#if defined(__has_builtin)
#if __has_builtin(__builtin_amdgcn_raw_buffer_load_b64) && __has_builtin(__builtin_amdgcn_make_buffer_rsrc)
#define USE_BUFLOAD 1
#endif
#endif

__device__ __forceinline__ float bf16_lo(unsigned int w) {
    return __uint_as_float(w << 16);
}
__device__ __forceinline__ float bf16_hi(unsigned int w) {
    return __uint_as_float(w & 0xffff0000u);
}

// ---- Pass 1: convert fp32 table -> packed bf16 table in workspace (L2-resident).
__global__ __launch_bounds__(256) void convert_bf16_kernel(
    const float* __restrict__ emb, ushort* __restrict__ tab, int n /* elements */)
{
    int i4 = (blockIdx.x * 256 + threadIdx.x) * 4;
    if (i4 + 3 < n) {
        float4 v = *reinterpret_cast<const float4*>(emb + i4);
        ushort4 o;
        o.x = __bfloat16_as_ushort(__float2bfloat16(v.x));
        o.y = __bfloat16_as_ushort(__float2bfloat16(v.y));
        o.z = __bfloat16_as_ushort(__float2bfloat16(v.z));
        o.w = __bfloat16_as_ushort(__float2bfloat16(v.w));
        *reinterpret_cast<ushort4*>(tab + i4) = o;
    } else if (i4 < n) {
        for (int k = i4; k < n; ++k)
            tab[k] = __bfloat16_as_ushort(__float2bfloat16(emb[k]));
    }
}

// ---- Pass 2: R7 structure; gathers via buffer_load sc0 (L1 bypass, L2 cached).
__global__ __launch_bounds__(THREADS, 6) void visit_encoder_bf16v8_kernel(
    const int* __restrict__ code_ids,
    const v2u* __restrict__ tab,     // bf16 table, row = 32B = 4 x v2u
    float* __restrict__ out,
    int B, int n_codes4)
{
    __shared__ v4i lcodes[ROWS_PER_BLOCK * ROW_STRIDE4];  // 17408 B

    const int t = threadIdx.x;
    const int block_row0 = blockIdx.x * ROWS_PER_BLOCK;

    // Stage 64 rows x 64 codes = 1024 int4; coalesced, regular (cached) loads.
    const v4i* src4 = reinterpret_cast<const v4i*>(code_ids);
    const int base4 = blockIdx.x * (ROWS_PER_BLOCK * SEQ_L / 4);
    #pragma unroll
    for (int k = 0; k < 4; ++k) {
        int j = t + THREADS * k;                 // 0..1023
        int gj = base4 + j;
        if (gj >= n_codes4) gj = n_codes4 - 1;   // tail clamp (ids stay valid)
        v4i v = src4[gj];
        lcodes[(j >> 4) * ROW_STRIDE4 + (j & 15)] = v;
    }
    __syncthreads();

    const int r  = t >> 2;     // 0..63 row within block
    const int d4 = t & 3;      // quarter-row: dims 4*d4 .. 4*d4+3

#ifdef USE_BUFLOAD
    // SRD: base ptr, stride=0, num_records=0xFFFFFFFF (bounds off), raw dword
    __amdgpu_buffer_rsrc_t rsrc =
        __builtin_amdgcn_make_buffer_rsrc((void*)tab, (short)0,
                                          0xFFFFFFFFu, 0x00020000);
    const int d4off = d4 * 8;            // byte offset within 32B row
#define GATHER(c) __builtin_amdgcn_raw_buffer_load_b64(rsrc, (c) * 32 + d4off, 0, 1)
#else
    const v2u* tbase = tab + d4;
#define GATHER(c) (tbase[(size_t)(c) * 4])
#endif

    float acc[4] = {0.f, 0.f, 0.f, 0.f};
    int cnt = 0;

    // 5 batches of 12 codes (12 x 8B gathers in flight), then a tail of 4.
    #pragma unroll
    for (int b = 0; b < 5; ++b) {
        v4i c0 = lcodes[r * ROW_STRIDE4 + b * 3 + 0];
        v4i c1 = lcodes[r * ROW_STRIDE4 + b * 3 + 1];
        v4i c2 = lcodes[r * ROW_STRIDE4 + b * 3 + 2];
        int cc[12] = {c0.x, c0.y, c0.z, c0.w,
                      c1.x, c1.y, c1.z, c1.w,
                      c2.x, c2.y, c2.z, c2.w};
        v2u e[12];
        #pragma unroll
        for (int u = 0; u < 12; ++u) {
            e[u] = GATHER(cc[u]);
        }
        #pragma unroll
        for (int u = 0; u < 12; ++u) {
            float m = (cc[u] != PAD_IDX) ? 1.0f : 0.0f;
            acc[0] = fmaf(bf16_lo(e[u].x), m, acc[0]);
            acc[1] = fmaf(bf16_hi(e[u].x), m, acc[1]);
            acc[2] = fmaf(bf16_lo(e[u].y), m, acc[2]);
            acc[3] = fmaf(bf16_hi(e[u].y), m, acc[3]);
            cnt += (cc[u] != PAD_IDX);
        }
    }
    {   // tail: codes 60..63 (int4 index 15)
        v4i c0 = lcodes[r * ROW_STRIDE4 + 15];
        int cc[4] = {c0.x, c0.y, c0.z, c0.w};
        v2u e[4];
        #pragma unroll
        for (int u = 0; u < 4; ++u) e[u] = GATHER(cc[u]);
        #pragma unroll
        for (int u = 0; u < 4; ++u) {
            float m = (cc[u] != PAD_IDX) ? 1.0f : 0.0f;
            acc[0] = fmaf(bf16_lo(e[u].x), m, acc[0]);
            acc[1] = fmaf(bf16_hi(e[u].x), m, acc[1]);
            acc[2] = fmaf(bf16_lo(e[u].y), m, acc[2]);
            acc[3] = fmaf(bf16_hi(e[u].y), m, acc[3]);
            cnt += (cc[u] != PAD_IDX);
        }
    }
#undef GATHER

    const int row = block_row0 + r;
    if (row < B) {
        float inv = 1.0f / fmaxf((float)cnt, 1.0f);
        v4f o;
        o.x = acc[0]*inv; o.y = acc[1]*inv; o.z = acc[2]*inv; o.w = acc[3]*inv;
        v4f* op = reinterpret_cast<v4f*>(out) + (size_t)row * 4 + d4;
        __builtin_nontemporal_store(o, op);
    }
}

// ---- Fallback: direct fp32 gather (proven R2 kernel) if ws too small.
__global__ __launch_bounds__(256) void visit_encoder_f32_kernel(
    const int* __restrict__ code_ids,
    const float* __restrict__ emb,
    float* __restrict__ out,
    int B, int n_codes4)
{
    __shared__ int4 lcodes[64 * 17];
    const int t = threadIdx.x;
    const int block_row0 = blockIdx.x * 64;
    const int4* src4 = reinterpret_cast<const int4*>(code_ids);
    const int base4 = blockIdx.x * (64 * SEQ_L / 4);
    #pragma unroll
    for (int k = 0; k < 4; ++k) {
        int j = t + 256 * k;
        int gj = base4 + j;
        if (gj >= n_codes4) gj = n_codes4 - 1;
        lcodes[(j >> 4) * 17 + (j & 15)] = src4[gj];
    }
    __syncthreads();
    const int r  = t >> 2;
    const int d4 = t & 3;
    const float4* ebase = reinterpret_cast<const float4*>(emb) + d4;
    float4 acc = make_float4(0.f, 0.f, 0.f, 0.f);
    int cnt = 0;
    #pragma unroll
    for (int l4 = 0; l4 < 16; l4 += 2) {
        int4 ca = lcodes[r * 17 + l4];
        int4 cb = lcodes[r * 17 + l4 + 1];
        int csx[8] = {ca.x, ca.y, ca.z, ca.w, cb.x, cb.y, cb.z, cb.w};
        float4 e[8];
        #pragma unroll
        for (int u = 0; u < 8; ++u) e[u] = ebase[(size_t)csx[u] * 4];
        #pragma unroll
        for (int u = 0; u < 8; ++u) {
            float m = (csx[u] != PAD_IDX) ? 1.0f : 0.0f;
            acc.x = fmaf(e[u].x, m, acc.x);
            acc.y = fmaf(e[u].y, m, acc.y);
            acc.z = fmaf(e[u].z, m, acc.z);
            acc.w = fmaf(e[u].w, m, acc.w);
            cnt += (csx[u] != PAD_IDX);
        }
    }
    const int row = block_row0 + r;
    if (row < B) {
        float inv = 1.0f / fmaxf((float)cnt, 1.0f);
        float4 o;
        o.x = acc.x * inv; o.y = acc.y * inv; o.z = acc.z * inv; o.w = acc.w * inv;
        reinterpret_cast<float4*>(out)[(size_t)row * 4 + d4] = o;
    }
}

extern "C" void kernel_launch(void* const* d_in, const int* in_sizes, int n_in,
                              void* d_out, int out_size, void* d_ws, size_t ws_size,
                              hipStream_t stream) {
    const int*   code_ids = (const int*)d_in[0];
    const float* emb      = (const float*)d_in[1];
    float*       out      = (float*)d_out;

    const int total_codes = in_sizes[0];        // B * L
    const int B = total_codes / SEQ_L;
    const int n_codes4 = total_codes / 4;
    const int emb_elems = in_sizes[1];          // NUM_CODES * DIM

    const size_t tab_bytes = (size_t)emb_elems * sizeof(ushort);
    if (ws_size >= tab_bytes) {
        ushort* tab = (ushort*)d_ws;
        int n4 = (emb_elems + 3) / 4;
        convert_bf16_kernel<<<dim3((n4 + 255) / 256), dim3(256), 0, stream>>>(
            emb, tab, emb_elems);
        const int grid = (B + ROWS_PER_BLOCK - 1) / ROWS_PER_BLOCK;
        visit_encoder_bf16v8_kernel<<<dim3(grid), dim3(THREADS), 0, stream>>>(
            code_ids, (const v2u*)tab, out, B, n_codes4);
    } else {
        const int grid = (B + 63) / 64;
        visit_encoder_f32_kernel<<<dim3(grid), dim3(256), 0, stream>>>(
            code_ids, emb, out, B, n_codes4);
    }
}